// Round 4
// baseline (423.678 us; speedup 1.0000x reference)
//
#include <hip/hip_runtime.h>
#include <cstdint>
#include <cstddef>

// L1 attention scores on MI355X.
// out[b,s,t,h] = -(1/sqrt(D)) * sum_d |q[b,s,h,d] - k[b,t,h,d]|
// B=2, S=2048, H=8, D=32, fp32.
//
// Round 4: BARRIER-FREE restructure. R2 counters showed Occupancy=25%
// (2 waves/SIMD, both from the same block) + per-chunk __syncthreads whose
// implicit s_waitcnt vmcnt(0) drained stores+prefetch with no other wave
// runnable (~60% stall). Fix: 1 wave per block, each wave stages its own
// 8KB k-chunk into its own LDS buffer. Within one wave the DS pipe is
// in-order, so ds_write -> ds_read needs no barrier (wave-synchronous
// idiom; __builtin_amdgcn_wave_barrier() pins compiler ordering only).
// No s_barrier, no vmcnt(0) drains: stores fire and forget, prefetch
// (chunk c+1 in 8 f32x4 regs) has a full chunk of compute as slack.
// Cost: k re-read 4x from L2 (~22 TB/s aggregate < 34.5 ceiling).
//
// Rotation swizzle kept: element (row,dv) at f32x4 idx row*8 + ((dv+row)&7);
// staged writes (g4 = 64j+lane -> row=8j+(lane>>3), dv=lane&7) and compute
// reads (row=lane, dv=0..7) both hit all 8 bank-quads per 8-lane phase.

#define S_DIM 2048
#define H_DIM 8
#define D_DIM 32
#define RS 4          // s-values per thread (block = 1 wave covers 4 s)
#define TSPLIT 8      // t-range split across blocks
#define TCHUNK 8      // t-values staged per LDS chunk
#define NTHREADS 64   // one wave
#define NCH ((S_DIM / TSPLIT) / TCHUNK)   // 32 chunks

typedef float f32x4 __attribute__((ext_vector_type(4)));

__global__ __launch_bounds__(NTHREADS) void l1attn_kernel(
    const float* __restrict__ q, const float* __restrict__ k,
    float* __restrict__ out)
{
  __shared__ f32x4 ldsk[TCHUNK * H_DIM * D_DIM / 4];  // 512 f32x4 = 8 KB

  const int lane = threadIdx.x;      // 0..63

  // bid = ((b*8 + tq) * 512) + sg : sg fastest so consecutive blocks share
  // the same 256KB k-slice (L2 locality) and stream q sequentially.
  const int bid = blockIdx.x;
  const int b   = bid >> 12;         // 4096 blocks per batch element
  const int tq  = (bid >> 9) & 7;    // t-eighth
  const int sg  = bid & 511;         // s-group (4 s each)

  const int h      = lane & 7;
  const int t_sub  = lane >> 3;
  const int s_base = sg * RS;
  const int t0     = tq * (S_DIM / TSPLIT);   // 256 * tq

  // ---- q fragments -> registers (128 VGPRs, held for whole block) ----
  f32x4 qf[RS][8];
  {
    const float* qb = q + (size_t)b * S_DIM * (H_DIM * D_DIM);
#pragma unroll
    for (int i = 0; i < RS; ++i) {
      const f32x4* qr = (const f32x4*)(qb +
          (size_t)(s_base + i) * (H_DIM * D_DIM) + h * D_DIM);
#pragma unroll
      for (int dv = 0; dv < 8; ++dv)
        qf[i][dv] = qr[dv];
    }
  }

  const f32x4* kbv = (const f32x4*)(k + (size_t)b * S_DIM * (H_DIM * D_DIM));

  // Staging: lane handles g4 = 64*j + lane (contiguous 1KB per inst).
  // Swizzled LDS dest: 64*j + f4b0 where f4b0 = (lane>>3)*8 + ((lane&7)+(lane>>3))&7
  // (the 8j term drops mod 8, so the per-lane base is loop-invariant).
  const int f4b0 = ((lane >> 3) << 3) | (((lane & 7) + (lane >> 3)) & 7);

  // Compute-side read addresses: (row=lane, dv).
  int rd[8];
#pragma unroll
  for (int dv = 0; dv < 8; ++dv)
    rd[dv] = (lane << 3) | ((dv + lane) & 7);

  // ---- prologue: chunk 0 -> prefetch regs ----
  f32x4 st[8];
  {
    const f32x4* kc = kbv + ((size_t)t0 << 6);   // t0 * 256 floats / 4
#pragma unroll
    for (int j = 0; j < 8; ++j)
      st[j] = kc[(j << 6) + lane];
  }

  const float nscale = -0.17677669529663687f;  // -1/sqrt(32)
  float* optr = out +
      ((size_t)(b * S_DIM + s_base) * S_DIM + (size_t)(t0 + t_sub)) * H_DIM + h;

  for (int c = 0; c < NCH; ++c) {
    // stage chunk c from regs into LDS (waits the global loads via vmcnt)
#pragma unroll
    for (int j = 0; j < 8; ++j)
      ldsk[(j << 6) + f4b0] = st[j];

    __builtin_amdgcn_wave_barrier();   // compiler: reads stay below writes

    if (c + 1 < NCH) {                 // issue prefetch of chunk c+1
      const f32x4* kn = kbv + ((size_t)(t0 + (c + 1) * TCHUNK) << 6);
#pragma unroll
      for (int j = 0; j < 8; ++j)
        st[j] = kn[(j << 6) + lane];
    }

    float acc0 = 0.f, acc1 = 0.f, acc2 = 0.f, acc3 = 0.f;
#pragma unroll
    for (int dv = 0; dv < 8; ++dv) {
      const f32x4 kf = ldsk[rd[dv]];   // swizzled ds_read_b128, conflict-free
      acc0 += __builtin_fabsf(qf[0][dv].x - kf.x) + __builtin_fabsf(qf[0][dv].y - kf.y)
            + __builtin_fabsf(qf[0][dv].z - kf.z) + __builtin_fabsf(qf[0][dv].w - kf.w);
      acc1 += __builtin_fabsf(qf[1][dv].x - kf.x) + __builtin_fabsf(qf[1][dv].y - kf.y)
            + __builtin_fabsf(qf[1][dv].z - kf.z) + __builtin_fabsf(qf[1][dv].w - kf.w);
      acc2 += __builtin_fabsf(qf[2][dv].x - kf.x) + __builtin_fabsf(qf[2][dv].y - kf.y)
            + __builtin_fabsf(qf[2][dv].z - kf.z) + __builtin_fabsf(qf[2][dv].w - kf.w);
      acc3 += __builtin_fabsf(qf[3][dv].x - kf.x) + __builtin_fabsf(qf[3][dv].y - kf.y)
            + __builtin_fabsf(qf[3][dv].z - kf.z) + __builtin_fabsf(qf[3][dv].w - kf.w);
    }

    __builtin_amdgcn_wave_barrier();   // next iter's writes stay below reads

    // coalesced dword stores: consecutive lanes -> consecutive (t,h) addrs
    float* o = optr + (size_t)(c << 6);          // c * TCHUNK * H_DIM
    o[0]                         = acc0 * nscale;
    o[(size_t)1 * S_DIM * H_DIM] = acc1 * nscale;
    o[(size_t)2 * S_DIM * H_DIM] = acc2 * nscale;
    o[(size_t)3 * S_DIM * H_DIM] = acc3 * nscale;
  }
}

extern "C" void kernel_launch(void* const* d_in, const int* in_sizes, int n_in,
                              void* d_out, int out_size, void* d_ws, size_t ws_size,
                              hipStream_t stream) {
  const float* q = (const float*)d_in[0];
  const float* k = (const float*)d_in[1];
  float* out = (float*)d_out;
  const int B = 2;
  dim3 grid(B * TSPLIT * (S_DIM / RS / NTHREADS * NTHREADS) / 64 * 64 / 8 * 8);
  // = B * 8 * 512 = 8192 one-wave blocks
  grid.x = B * TSPLIT * (S_DIM / RS);
  dim3 block(NTHREADS);
  l1attn_kernel<<<grid, block, 0, stream>>>(q, k, out);
}